// Round 4
// baseline (395.938 us; speedup 1.0000x reference)
//
#include <hip/hip_runtime.h>
#include <hip/hip_bf16.h>

#define SEQ   2048
#define BATCH 2
#define NHEAD 16
#define HDIM  64
#define CDIM  1024
#define QKV_F 5120
#define SCALE 0.125f
#define LOG2E 1.44269504f
#define EPSV  1e-5f

typedef __bf16 bf16;
typedef __bf16 bf16x4 __attribute__((ext_vector_type(4)));
typedef __bf16 bf16x8 __attribute__((ext_vector_type(8)));
typedef float  f32x4  __attribute__((ext_vector_type(4)));
typedef float  f32x16 __attribute__((ext_vector_type(16)));

#define MFMA16(a, b, c) __builtin_amdgcn_mfma_f32_16x16x32_bf16(a, b, c, 0, 0, 0)
#define MFMA32(a, b, c) __builtin_amdgcn_mfma_f32_32x32x16_bf16(a, b, c, 0, 0, 0)

__device__ __forceinline__ unsigned pkbf(float a, float b) {
    union { bf16 h[2]; unsigned u; } t;
    t.h[0] = (bf16)a; t.h[1] = (bf16)b;
    return t.u;
}
__device__ __forceinline__ unsigned short bfbits(float a) {
    union { bf16 h; unsigned short u; } t;
    t.h = (bf16)a;
    return t.u;
}
__device__ __forceinline__ void gload16(const void* g, void* l) {
    __builtin_amdgcn_global_load_lds(
        (const __attribute__((address_space(1))) unsigned int*)g,
        (__attribute__((address_space(3))) unsigned int*)l, 16, 0, 0);
}

// ---------------------------------------------------------------------------
// f32 -> bf16 convert, 8 elems/thread.
// ---------------------------------------------------------------------------
__global__ __launch_bounds__(256) void cvt_bf16(
    const float* __restrict__ s, bf16* __restrict__ d)
{
    const int i = (blockIdx.x * 256 + threadIdx.x) * 8;
    float4 a = *(const float4*)(s + i);
    float4 b = *(const float4*)(s + i + 4);
    bf16x8 t;
    t[0] = (bf16)a.x; t[1] = (bf16)a.y; t[2] = (bf16)a.z; t[3] = (bf16)a.w;
    t[4] = (bf16)b.x; t[5] = (bf16)b.y; t[6] = (bf16)b.z; t[7] = (bf16)b.w;
    *(bf16x8*)(d + i) = t;
}

// ---------------------------------------------------------------------------
// m97-structure GEMM: C = A(MxK) * B(NnxK)^T, bf16 in, global_load_lds x16.
// ---------------------------------------------------------------------------
template <int EPI>
__global__ __launch_bounds__(256) void gemm_lds(
    const bf16* __restrict__ A, const bf16* __restrict__ Bw,
    const float* __restrict__ bias,
    bf16* __restrict__ outq, float* __restrict__ outp,
    int M, int Nn, int K)
{
    __shared__ __align__(16) bf16 As[128 * 64];
    __shared__ __align__(16) bf16 Bs[128 * 64];

    const int tid  = threadIdx.x;
    const int lane = tid & 63;
    const int wave = tid >> 6;
    const int wr = wave >> 1, wc = wave & 1;
    const int g = lane >> 4, fr = lane & 15;
    const int m0 = blockIdx.y * 128;
    const int n0 = blockIdx.x * 128;

    const int lrow = lane >> 3;
    const int lcol = (lane & 7) << 3;

    f32x4 acc[4][4];
#pragma unroll
    for (int m = 0; m < 4; ++m)
#pragma unroll
        for (int n = 0; n < 4; ++n) acc[m][n] = f32x4{0.f, 0.f, 0.f, 0.f};

    const int nkt = K >> 6;
    for (int kt = 0; kt < nkt; ++kt) {
        const int k0 = kt << 6;
        __syncthreads();
#pragma unroll
        for (int i = 0; i < 4; ++i) {
            const int chunk = wave * 4 + i;
            const int row = chunk * 8 + lrow;
            gload16(A + (size_t)(m0 + row) * K + k0 + lcol, As + chunk * 512);
            gload16(Bw + (size_t)(n0 + row) * K + k0 + lcol, Bs + chunk * 512);
        }
        __syncthreads();
#pragma unroll
        for (int ks = 0; ks < 2; ++ks) {
            bf16x8 af[4], bfr[4];
#pragma unroll
            for (int m = 0; m < 4; ++m)
                af[m] = *(const bf16x8*)(As + (wr * 64 + m * 16 + fr) * 64 + ks * 32 + g * 8);
#pragma unroll
            for (int n = 0; n < 4; ++n)
                bfr[n] = *(const bf16x8*)(Bs + (wc * 64 + n * 16 + fr) * 64 + ks * 32 + g * 8);
#pragma unroll
            for (int m = 0; m < 4; ++m)
#pragma unroll
                for (int n = 0; n < 4; ++n)
                    acc[m][n] = MFMA16(af[m], bfr[n], acc[m][n]);
        }
    }

#pragma unroll
    for (int m = 0; m < 4; ++m) {
#pragma unroll
        for (int n = 0; n < 4; ++n) {
            const int row0 = m0 + wr * 64 + m * 16 + g * 4;
            const int col  = n0 + wc * 64 + n * 16 + fr;
            if (EPI == 0) {
                const int bb = row0 >> 11, nn = row0 & (SEQ - 1);
                const int sI = col >> 10, rem = col & (CDIM - 1);
                const int hh = rem >> 6, dd = rem & 63;
                const size_t base = ((size_t)((sI * BATCH + bb) * NHEAD + hh)) << 17;
                if (sI == 4) {
                    ushort4 u;
                    u.x = bfbits(acc[m][n][0]);
                    u.y = bfbits(acc[m][n][1]);
                    u.z = bfbits(acc[m][n][2]);
                    u.w = bfbits(acc[m][n][3]);
                    *(ushort4*)(outq + base + ((size_t)dd << 11) + nn) = u;
                } else {
                    const float sc = (sI < 2) ? SCALE * LOG2E : 1.f;
#pragma unroll
                    for (int r = 0; r < 4; ++r)
                        outq[base + ((size_t)(nn + r) << 6) + dd] = (bf16)(acc[m][n][r] * sc);
                }
            } else {
#pragma unroll
                for (int r = 0; r < 4; ++r)
                    outp[(size_t)(row0 + r) * Nn + col] = acc[m][n][r] + bias[col];
            }
        }
    }
}

// ---------------------------------------------------------------------------
// Differential flash attention with KV-split (flash-decoding style).
// Block: 8 waves = 2 groups x 4 waves. Group handles same 128 Q-rows for one
// KV half; partials merged in LDS. grid = (SEQ/128, BATCH*NHEAD) = 2 blk/CU.
// S^T = mfma32(K,Q); O^T = mfma32(V^T,P); softmax in exp2 domain.
// ---------------------------------------------------------------------------
__device__ __forceinline__ void attn_state(
    const char* __restrict__ Ks, const bf16x8* qf, const bf16x8 (*vf)[2],
    int lq, int hi, int s32,
    f32x16& oa, f32x16& ob, float& mS, float& lS)
{
    f32x16 s;
#pragma unroll
    for (int r = 0; r < 16; ++r) s[r] = 0.f;
    const int krow = s32 * 32 + lq;
    const int ksw  = (krow & 7) << 4;
    __builtin_amdgcn_s_setprio(1);
#pragma unroll
    for (int ks = 0; ks < 4; ++ks) {
        bf16x8 kf = *(const bf16x8*)(Ks + krow * 128 + ((ks * 32 + hi * 16) ^ ksw));
        s = MFMA32(kf, qf[ks], s);
    }
    __builtin_amdgcn_s_setprio(0);
    // tree max (depth 4)
    float t0 = fmaxf(s[0], s[1]),  t1 = fmaxf(s[2], s[3]);
    float t2 = fmaxf(s[4], s[5]),  t3 = fmaxf(s[6], s[7]);
    float t4 = fmaxf(s[8], s[9]),  t5 = fmaxf(s[10], s[11]);
    float t6 = fmaxf(s[12], s[13]), t7 = fmaxf(s[14], s[15]);
    t0 = fmaxf(t0, t4); t1 = fmaxf(t1, t5); t2 = fmaxf(t2, t6); t3 = fmaxf(t3, t7);
    float pm = fmaxf(fmaxf(t0, t2), fmaxf(t1, t3));
    pm = fmaxf(pm, __shfl_xor(pm, 32));
    // defer-max (threshold 8 ln = 11.54 log2)
    if (!__all(pm <= mS + 8.f * LOG2E)) {
        float mn = fmaxf(mS, pm);
        float alpha = __builtin_amdgcn_exp2f(mS - mn);
        lS *= alpha;
        oa *= alpha;
        ob *= alpha;
        mS = mn;
    }
#pragma unroll
    for (int r = 0; r < 16; ++r) s[r] = __builtin_amdgcn_exp2f(s[r] - mS);
    // tree sum
    float u0 = s[0] + s[1],  u1 = s[2] + s[3];
    float u2 = s[4] + s[5],  u3 = s[6] + s[7];
    float u4 = s[8] + s[9],  u5 = s[10] + s[11];
    float u6 = s[12] + s[13], u7 = s[14] + s[15];
    u0 += u4; u1 += u5; u2 += u6; u3 += u7;
    float rs = (u0 + u2) + (u1 + u3);
    rs += __shfl_xor(rs, 32);
    lS += rs;
#pragma unroll
    for (int s16 = 0; s16 < 2; ++s16) {
        unsigned X = pkbf(s[s16 * 8 + 0], s[s16 * 8 + 1]);
        unsigned Z = pkbf(s[s16 * 8 + 2], s[s16 * 8 + 3]);
        unsigned Y = pkbf(s[s16 * 8 + 4], s[s16 * 8 + 5]);
        unsigned W = pkbf(s[s16 * 8 + 6], s[s16 * 8 + 7]);
        auto xy = __builtin_amdgcn_permlane32_swap(X, Y, false, false);
        auto zw = __builtin_amdgcn_permlane32_swap(Z, W, false, false);
        union { unsigned u[4]; bf16x8 v; } pf;
        pf.u[0] = xy[0]; pf.u[1] = zw[0]; pf.u[2] = xy[1]; pf.u[3] = zw[1];
        __builtin_amdgcn_s_setprio(1);
        oa = MFMA32(vf[0][s16], pf.v, oa);
        ob = MFMA32(vf[1][s16], pf.v, ob);
        __builtin_amdgcn_s_setprio(0);
    }
}

__global__ __launch_bounds__(512, 4) void diff_attn(
    const bf16* __restrict__ qkv,
    const float* __restrict__ lq1, const float* __restrict__ lk1,
    const float* __restrict__ lq2, const float* __restrict__ lk2,
    float* __restrict__ attn_out)
{
    __shared__ __align__(16) char SMEM[49152];   // [grp][K1|K2|Vt][8192]

    const int tid = threadIdx.x;
    const int lane = tid & 63, wave = tid >> 6;
    const int wg = wave & 3, grp = wave >> 2;
    const int lq = lane & 31, hi = lane >> 5;
    const int bh = blockIdx.y, b = bh >> 4, h = bh & 15;
    const int q0w = blockIdx.x * 128 + wg * 32;
    const int kv0 = grp * (SEQ / 2);

    char* Ks1 = SMEM + grp * 24576;
    char* Ks2 = Ks1 + 8192;
    char* Vts = Ks1 + 16384;

    float ls1 = 0.f, ls2 = 0.f;
    for (int i = 0; i < HDIM; ++i) { ls1 += lq1[i] * lk1[i]; ls2 += lq2[i] * lk2[i]; }
    const float lam = __expf(ls1) - __expf(ls2) + 0.8f;

    const size_t HS = (size_t)SEQ * HDIM;
    const char* q1p = (const char*)(qkv + ((size_t)((0 * BATCH + b) * NHEAD + h)) * HS);
    const char* q2p = (const char*)(qkv + ((size_t)((1 * BATCH + b) * NHEAD + h)) * HS);
    const char* k1p = (const char*)(qkv + ((size_t)((2 * BATCH + b) * NHEAD + h)) * HS);
    const char* k2p = (const char*)(qkv + ((size_t)((3 * BATCH + b) * NHEAD + h)) * HS);
    const char* vtp = (const char*)(qkv + ((size_t)((4 * BATCH + b) * NHEAD + h)) * HS);

    bf16x8 qf1[4], qf2[4];
#pragma unroll
    for (int ks = 0; ks < 4; ++ks) {
        qf1[ks] = *(const bf16x8*)(q1p + (size_t)(q0w + lq) * 128 + ks * 32 + hi * 16);
        qf2[ks] = *(const bf16x8*)(q2p + (size_t)(q0w + lq) * 128 + ks * 32 + hi * 16);
    }

    f32x16 o1a, o1b, o2a, o2b;
#pragma unroll
    for (int r = 0; r < 16; ++r) { o1a[r] = 0.f; o1b[r] = 0.f; o2a[r] = 0.f; o2b[r] = 0.f; }
    float m1 = -1e30f, l1 = 0.f, m2 = -1e30f, l2 = 0.f;

    // staging: per-lane pre-swizzled global source, linear LDS dest (rule 21)
    const int lrow8 = lane >> 3;                      // row within 8-row chunk
    const int scol  = ((lane & 7) ^ lrow8) << 4;      // swizzled source byte col

    for (int kt = 0; kt < SEQ / 2 / 64; ++kt) {
        __syncthreads();
#pragma unroll
        for (int i = 0; i < 6; ++i) {
            const int c = wg * 6 + i;                 // 0..23, wave-uniform
            const int tile = c >> 3, ch = c & 7;
            const int row = ch * 8 + lrow8;
            char* ldst = Ks1 + tile * 8192 + ch * 1024;
            const char* src;
            if (tile < 2) {
                const char* kb = tile ? k2p : k1p;
                src = kb + (size_t)(kv0 + kt * 64 + row) * 128 + scol;
            } else {
                src = vtp + (size_t)row * (SEQ * 2) + (size_t)(kv0 + kt * 64) * 2 + scol;
            }
            gload16(src, ldst);
        }
        __syncthreads();

#pragma unroll
        for (int s32 = 0; s32 < 2; ++s32) {
            bf16x8 vf[2][2];
#pragma unroll
            for (int dt = 0; dt < 2; ++dt) {
                const int vrow = dt * 32 + lq;
                const int vsw  = (vrow & 7) << 4;
#pragma unroll
                for (int s16 = 0; s16 < 2; ++s16)
                    vf[dt][s16] = *(const bf16x8*)(Vts + vrow * 128 +
                                   ((s32 * 64 + s16 * 32 + hi * 16) ^ vsw));
            }
            attn_state(Ks1, qf1, vf, lq, hi, s32, o1a, o1b, m1, l1);
            attn_state(Ks2, qf2, vf, lq, hi, s32, o2a, o2b, m2, l2);
        }
    }

    // ---- merge the two KV halves (group B -> LDS, group A merges) ----
    float* MF = (float*)SMEM;            // [4][256+] m1,l1,m2,l2 planes
    float* OF = (float*)(SMEM + 4096);   // [32][256] o planes
    const int mbase = wg * 64 + lane;

    __syncthreads();
    if (grp == 1) {
        MF[0 * 256 + mbase] = m1;
        MF[1 * 256 + mbase] = l1;
        MF[2 * 256 + mbase] = m2;
        MF[3 * 256 + mbase] = l2;
#pragma unroll
        for (int r = 0; r < 16; ++r) {
            OF[r * 256 + mbase]        = o1a[r];
            OF[(16 + r) * 256 + mbase] = o1b[r];
        }
    }
    __syncthreads();
    float aA1, aB1, aA2, aB2;
    if (grp == 0) {
        const float mB1 = MF[0 * 256 + mbase], lB1 = MF[1 * 256 + mbase];
        const float mB2 = MF[2 * 256 + mbase], lB2 = MF[3 * 256 + mbase];
        const float mn1 = fmaxf(m1, mB1), mn2 = fmaxf(m2, mB2);
        aA1 = __builtin_amdgcn_exp2f(m1 - mn1);
        aB1 = __builtin_amdgcn_exp2f(mB1 - mn1);
        aA2 = __builtin_amdgcn_exp2f(m2 - mn2);
        aB2 = __builtin_amdgcn_exp2f(mB2 - mn2);
        l1 = l1 * aA1 + lB1 * aB1;
        l2 = l2 * aA2 + lB2 * aB2;
#pragma unroll
        for (int r = 0; r < 16; ++r) {
            o1a[r] = o1a[r] * aA1 + OF[r * 256 + mbase] * aB1;
            o1b[r] = o1b[r] * aA1 + OF[(16 + r) * 256 + mbase] * aB1;
        }
    }
    __syncthreads();
    if (grp == 1) {
#pragma unroll
        for (int r = 0; r < 16; ++r) {
            OF[r * 256 + mbase]        = o2a[r];
            OF[(16 + r) * 256 + mbase] = o2b[r];
        }
    }
    __syncthreads();
    if (grp == 0) {
#pragma unroll
        for (int r = 0; r < 16; ++r) {
            o2a[r] = o2a[r] * aA2 + OF[r * 256 + mbase] * aB2;
            o2b[r] = o2b[r] * aA2 + OF[(16 + r) * 256 + mbase] * aB2;
        }
        const float i1 = 1.f / l1;
        const float i2 = lam / l2;
        const int nq = q0w + lq;
        float* op = attn_out + ((size_t)(b * SEQ + nq)) * CDIM + h * HDIM;
#pragma unroll
        for (int dt = 0; dt < 2; ++dt) {
            const f32x16& a1 = dt ? o1b : o1a;
            const f32x16& a2 = dt ? o2b : o2a;
#pragma unroll
            for (int rq = 0; rq < 4; ++rq) {
                const int d0 = dt * 32 + rq * 8 + hi * 4;
                float4 o;
                o.x = a1[rq * 4 + 0] * i1 - i2 * a2[rq * 4 + 0];
                o.y = a1[rq * 4 + 1] * i1 - i2 * a2[rq * 4 + 1];
                o.z = a1[rq * 4 + 2] * i1 - i2 * a2[rq * 4 + 2];
                o.w = a1[rq * 4 + 3] * i1 - i2 * a2[rq * 4 + 3];
                *(float4*)(op + d0) = o;
            }
        }
    }
}

// ---------------------------------------------------------------------------
// RMSNorm over last dim (1024) + 0.2 scale, fp32 in -> bf16 out.
// ---------------------------------------------------------------------------
__global__ __launch_bounds__(256) void rmsnorm_bf16(
    const float* __restrict__ in, bf16* __restrict__ out)
{
    __shared__ float red[4];
    const int row = blockIdx.x, tid = threadIdx.x;
    const float4 v = ((const float4*)(in + (size_t)row * CDIM))[tid];
    float ss = v.x * v.x + v.y * v.y + v.z * v.z + v.w * v.w;
#pragma unroll
    for (int m = 1; m < 64; m <<= 1) ss += __shfl_xor(ss, m);
    if ((tid & 63) == 0) red[tid >> 6] = ss;
    __syncthreads();
    float tot = red[0] + red[1] + red[2] + red[3];
    float sc = rsqrtf(tot * (1.f / CDIM) + EPSV) * 0.2f;
    bf16x4 o;
    o[0] = (bf16)(v.x * sc); o[1] = (bf16)(v.y * sc);
    o[2] = (bf16)(v.z * sc); o[3] = (bf16)(v.w * sc);
    ((bf16x4*)(out + (size_t)row * CDIM))[tid] = o;
}

extern "C" void kernel_launch(void* const* d_in, const int* in_sizes, int n_in,
                              void* d_out, int out_size, void* d_ws, size_t ws_size,
                              hipStream_t stream)
{
    (void)in_sizes; (void)n_in; (void)out_size; (void)ws_size;
    const float* x      = (const float*)d_in[0];
    const float* qkv_w  = (const float*)d_in[1];
    const float* proj_w = (const float*)d_in[2];
    const float* proj_b = (const float*)d_in[3];
    const float* lq1    = (const float*)d_in[4];
    const float* lk1    = (const float*)d_in[5];
    const float* lq2    = (const float*)d_in[6];
    const float* lk2    = (const float*)d_in[7];
    float* out = (float*)d_out;

    char* ws = (char*)d_ws;
    bf16*  qkv_t    = (bf16*)ws;
    bf16*  attn_b   = (bf16*)ws;
    float* attn_out = (float*)(ws + (size_t)40 * 1024 * 1024);
    bf16*  x_b      = (bf16*)(ws + (size_t)40 * 1024 * 1024);
    bf16*  qkvw_b   = (bf16*)(ws + (size_t)56 * 1024 * 1024);
    bf16*  projw_b  = (bf16*)(ws + (size_t)66 * 1024 * 1024);

    dim3 blk(256);
    cvt_bf16<<<dim3((BATCH * SEQ * CDIM) / 2048), blk, 0, stream>>>(x, x_b);
    cvt_bf16<<<dim3((QKV_F * CDIM) / 2048), blk, 0, stream>>>(qkv_w, qkvw_b);
    cvt_bf16<<<dim3((CDIM * CDIM) / 2048), blk, 0, stream>>>(proj_w, projw_b);
    gemm_lds<0><<<dim3(QKV_F / 128, (BATCH * SEQ) / 128), blk, 0, stream>>>(
        x_b, qkvw_b, nullptr, qkv_t, nullptr, BATCH * SEQ, QKV_F, CDIM);
    diff_attn<<<dim3(SEQ / 128, BATCH * NHEAD), dim3(512), 0, stream>>>(
        qkv_t, lq1, lk1, lq2, lk2, attn_out);
    rmsnorm_bf16<<<dim3(BATCH * SEQ), blk, 0, stream>>>(attn_out, attn_b);
    gemm_lds<1><<<dim3(CDIM / 128, (BATCH * SEQ) / 128), blk, 0, stream>>>(
        attn_b, projw_b, proj_b, nullptr, out, BATCH * SEQ, CDIM, CDIM);
}

// Round 5
// 229.675 us; speedup vs baseline: 1.7239x; 1.7239x over previous
//
#include <hip/hip_runtime.h>
#include <hip/hip_bf16.h>

#define SEQ   2048
#define BATCH 2
#define NHEAD 16
#define HDIM  64
#define CDIM  1024
#define QKV_F 5120
#define SCALE 0.125f
#define LOG2E 1.44269504f
#define EPSV  1e-5f

typedef __bf16 bf16;
typedef __bf16 bf16x4 __attribute__((ext_vector_type(4)));
typedef __bf16 bf16x8 __attribute__((ext_vector_type(8)));
typedef float  f32x4  __attribute__((ext_vector_type(4)));

#define MFMA16(a, b, c) __builtin_amdgcn_mfma_f32_16x16x32_bf16(a, b, c, 0, 0, 0)

__device__ __forceinline__ unsigned pkbf(float a, float b) {
    union { bf16 h[2]; unsigned u; } t;
    t.h[0] = (bf16)a; t.h[1] = (bf16)b;
    return t.u;
}
__device__ __forceinline__ unsigned short bfbits(float a) {
    union { bf16 h; unsigned short u; } t;
    t.h = (bf16)a;
    return t.u;
}
__device__ __forceinline__ void gload16(const void* g, void* l) {
    __builtin_amdgcn_global_load_lds(
        (const __attribute__((address_space(1))) unsigned int*)g,
        (__attribute__((address_space(3))) unsigned int*)l, 16, 0, 0);
}

// ---------------------------------------------------------------------------
// f32 -> bf16 convert, 8 elems/thread.
// ---------------------------------------------------------------------------
__global__ __launch_bounds__(256) void cvt_bf16(
    const float* __restrict__ s, bf16* __restrict__ d)
{
    const int i = (blockIdx.x * 256 + threadIdx.x) * 8;
    float4 a = *(const float4*)(s + i);
    float4 b = *(const float4*)(s + i + 4);
    bf16x8 t;
    t[0] = (bf16)a.x; t[1] = (bf16)a.y; t[2] = (bf16)a.z; t[3] = (bf16)a.w;
    t[4] = (bf16)b.x; t[5] = (bf16)b.y; t[6] = (bf16)b.z; t[7] = (bf16)b.w;
    *(bf16x8*)(d + i) = t;
}

// ---------------------------------------------------------------------------
// m97-structure GEMM: C = A(MxK) * B(NnxK)^T, bf16 in, global_load_lds x16.
// EPI 0: scatter qkv (q1/q2 scaled by SCALE*LOG2E, V transposed [d][n]).
// EPI 1: fp32 + bias.
// ---------------------------------------------------------------------------
template <int EPI>
__global__ __launch_bounds__(256) void gemm_lds(
    const bf16* __restrict__ A, const bf16* __restrict__ Bw,
    const float* __restrict__ bias,
    bf16* __restrict__ outq, float* __restrict__ outp,
    int M, int Nn, int K)
{
    __shared__ __align__(16) bf16 As[128 * 64];
    __shared__ __align__(16) bf16 Bs[128 * 64];

    const int tid  = threadIdx.x;
    const int lane = tid & 63;
    const int wave = tid >> 6;
    const int wr = wave >> 1, wc = wave & 1;
    const int g = lane >> 4, fr = lane & 15;
    const int m0 = blockIdx.y * 128;
    const int n0 = blockIdx.x * 128;

    const int lrow = lane >> 3;
    const int lcol = (lane & 7) << 3;

    f32x4 acc[4][4];
#pragma unroll
    for (int m = 0; m < 4; ++m)
#pragma unroll
        for (int n = 0; n < 4; ++n) acc[m][n] = f32x4{0.f, 0.f, 0.f, 0.f};

    const int nkt = K >> 6;
    for (int kt = 0; kt < nkt; ++kt) {
        const int k0 = kt << 6;
        __syncthreads();
#pragma unroll
        for (int i = 0; i < 4; ++i) {
            const int chunk = wave * 4 + i;
            const int row = chunk * 8 + lrow;
            gload16(A + (size_t)(m0 + row) * K + k0 + lcol, As + chunk * 512);
            gload16(Bw + (size_t)(n0 + row) * K + k0 + lcol, Bs + chunk * 512);
        }
        __syncthreads();
#pragma unroll
        for (int ks = 0; ks < 2; ++ks) {
            bf16x8 af[4], bfr[4];
#pragma unroll
            for (int m = 0; m < 4; ++m)
                af[m] = *(const bf16x8*)(As + (wr * 64 + m * 16 + fr) * 64 + ks * 32 + g * 8);
#pragma unroll
            for (int n = 0; n < 4; ++n)
                bfr[n] = *(const bf16x8*)(Bs + (wc * 64 + n * 16 + fr) * 64 + ks * 32 + g * 8);
#pragma unroll
            for (int m = 0; m < 4; ++m)
#pragma unroll
                for (int n = 0; n < 4; ++n)
                    acc[m][n] = MFMA16(af[m], bfr[n], acc[m][n]);
        }
    }

#pragma unroll
    for (int m = 0; m < 4; ++m) {
#pragma unroll
        for (int n = 0; n < 4; ++n) {
            const int row0 = m0 + wr * 64 + m * 16 + g * 4;
            const int col  = n0 + wc * 64 + n * 16 + fr;
            if (EPI == 0) {
                const int bb = row0 >> 11, nn = row0 & (SEQ - 1);
                const int sI = col >> 10, rem = col & (CDIM - 1);
                const int hh = rem >> 6, dd = rem & 63;
                const size_t base = ((size_t)((sI * BATCH + bb) * NHEAD + hh)) << 17;
                if (sI == 4) {
                    ushort4 u;
                    u.x = bfbits(acc[m][n][0]);
                    u.y = bfbits(acc[m][n][1]);
                    u.z = bfbits(acc[m][n][2]);
                    u.w = bfbits(acc[m][n][3]);
                    *(ushort4*)(outq + base + ((size_t)dd << 11) + nn) = u;
                } else {
                    const float sc = (sI < 2) ? SCALE * LOG2E : 1.f;
#pragma unroll
                    for (int r = 0; r < 4; ++r)
                        outq[base + ((size_t)(nn + r) << 6) + dd] = (bf16)(acc[m][n][r] * sc);
                }
            } else {
#pragma unroll
                for (int r = 0; r < 4; ++r)
                    outp[(size_t)(row0 + r) * Nn + col] = acc[m][n][r] + bias[col];
            }
        }
    }
}

// ---------------------------------------------------------------------------
// Differential flash attention, 16x16 MFMA variant (16 q-rows per wave).
//   S^T = mfma16(K, Q): col = q (lane&15), row = kv (g*4+r per 16-kv subtile)
//   O^T = mfma16(V^T, P): contraction index permuted so P-frag is lane-local:
//       kv(g,j) = 32G + 16*(j>>2) + 4g + (j&3); V^T LDS columns permuted
//       identically at staging -> PV sum over kv unchanged.
// Block = 4 waves x 16 q = 64 q. grid = (BH=32, SEQ/64=32) -> 1024 blocks,
// 4 blocks/CU (VGPR<=128, LDS 24KB). bh-major -> per-XCD KV L2 locality.
// ---------------------------------------------------------------------------
__global__ __launch_bounds__(256, 4) void diff_attn(
    const bf16* __restrict__ qkv,
    const float* __restrict__ lq1, const float* __restrict__ lk1,
    const float* __restrict__ lq2, const float* __restrict__ lk2,
    float* __restrict__ attn_out)
{
    __shared__ __align__(16) char K1s[8192];
    __shared__ __align__(16) char K2s[8192];
    __shared__ __align__(16) char Vts[8192];

    const int tid = threadIdx.x;
    const int lane = tid & 63, wave = tid >> 6;
    const int g = lane >> 4, fr = lane & 15;
    const int bh = blockIdx.x, b = bh >> 4, h = bh & 15;
    const int q0 = blockIdx.y * 64 + wave * 16;

    float ls1 = 0.f, ls2 = 0.f;
    for (int i = 0; i < HDIM; ++i) { ls1 += lq1[i] * lk1[i]; ls2 += lq2[i] * lk2[i]; }
    const float lam = __expf(ls1) - __expf(ls2) + 0.8f;

    const size_t HS = (size_t)SEQ * HDIM;
    const char* q1p = (const char*)(qkv + ((size_t)((0 * BATCH + b) * NHEAD + h)) * HS);
    const char* q2p = (const char*)(qkv + ((size_t)((1 * BATCH + b) * NHEAD + h)) * HS);
    const char* k1p = (const char*)(qkv + ((size_t)((2 * BATCH + b) * NHEAD + h)) * HS);
    const char* k2p = (const char*)(qkv + ((size_t)((3 * BATCH + b) * NHEAD + h)) * HS);
    const char* vtp = (const char*)(qkv + ((size_t)((4 * BATCH + b) * NHEAD + h)) * HS);

    // Q fragments (B-operand): lane (g,fr) holds Q[q0+fr][ks*32 + g*8 + j]
    bf16x8 qf1[2], qf2[2];
#pragma unroll
    for (int ks = 0; ks < 2; ++ks) {
        qf1[ks] = *(const bf16x8*)(q1p + (size_t)(q0 + fr) * 128 + ks * 64 + g * 16);
        qf2[ks] = *(const bf16x8*)(q2p + (size_t)(q0 + fr) * 128 + ks * 64 + g * 16);
    }

    f32x4 o1[4], o2[4];
#pragma unroll
    for (int d = 0; d < 4; ++d) { o1[d] = f32x4{0, 0, 0, 0}; o2[d] = f32x4{0, 0, 0, 0}; }
    float m1 = -1e30f, l1 = 0.f, m2 = -1e30f, l2 = 0.f;

    // K staging (gload16, pre-swizzled source, linear LDS dest)
    const int lrow8 = lane >> 3;
    const int scol  = ((lane & 7) ^ lrow8) << 4;
    // V staging (reg, permuted columns): thread handles d-row tid>>2, runs u
    const int vd = tid >> 2;
    const char* vsrc = vtp + (size_t)vd * (SEQ * 2);
    char* vdst = Vts + vd * 128;
    const int vswz = (vd & 7) << 4;

    // softmax + pack: produces 8 packed words {A0,B0,A1,B1, A2,B2,A3,B3}
    auto qk_sm = [&](const char* Ks, const bf16x8* qf, f32x4* o,
                     float& mS, float& lS, unsigned* pw) {
        f32x4 s0{0, 0, 0, 0}, s1{0, 0, 0, 0}, s2{0, 0, 0, 0}, s3{0, 0, 0, 0};
        __builtin_amdgcn_s_setprio(1);
#pragma unroll
        for (int ks = 0; ks < 2; ++ks) {
            const int c = (ks * 64 + g * 16);
            bf16x8 k0 = *(const bf16x8*)(Ks + (0 * 16 + fr) * 128 + (c ^ ((fr & 7) << 4)));
            bf16x8 k1 = *(const bf16x8*)(Ks + (1 * 16 + fr) * 128 + (c ^ ((fr & 7) << 4)));
            bf16x8 k2 = *(const bf16x8*)(Ks + (2 * 16 + fr) * 128 + (c ^ ((fr & 7) << 4)));
            bf16x8 k3 = *(const bf16x8*)(Ks + (3 * 16 + fr) * 128 + (c ^ ((fr & 7) << 4)));
            s0 = MFMA16(k0, qf[ks], s0);
            s1 = MFMA16(k1, qf[ks], s1);
            s2 = MFMA16(k2, qf[ks], s2);
            s3 = MFMA16(k3, qf[ks], s3);
        }
        __builtin_amdgcn_s_setprio(0);
        f32x4 t01 = __builtin_elementwise_max(s0, s1);
        f32x4 t23 = __builtin_elementwise_max(s2, s3);
        f32x4 t = __builtin_elementwise_max(t01, t23);
        float pm = fmaxf(fmaxf(t[0], t[1]), fmaxf(t[2], t[3]));
        pm = fmaxf(pm, __shfl_xor(pm, 16));
        pm = fmaxf(pm, __shfl_xor(pm, 32));
        if (!__all(pm <= mS + 8.f * LOG2E)) {
            float mn = fmaxf(mS, pm);
            float alpha = __builtin_amdgcn_exp2f(mS - mn);
            lS *= alpha;
#pragma unroll
            for (int d = 0; d < 4; ++d) o[d] *= alpha;
            mS = mn;
        }
#pragma unroll
        for (int r = 0; r < 4; ++r) {
            s0[r] = __builtin_amdgcn_exp2f(s0[r] - mS);
            s1[r] = __builtin_amdgcn_exp2f(s1[r] - mS);
            s2[r] = __builtin_amdgcn_exp2f(s2[r] - mS);
            s3[r] = __builtin_amdgcn_exp2f(s3[r] - mS);
        }
        f32x4 u01 = (s0 + s1) + (s2 + s3);
        float rs = (u01[0] + u01[1]) + (u01[2] + u01[3]);
        rs += __shfl_xor(rs, 16);
        rs += __shfl_xor(rs, 32);
        lS += rs;
        pw[0] = pkbf(s0[0], s0[1]); pw[1] = pkbf(s0[2], s0[3]);
        pw[2] = pkbf(s1[0], s1[1]); pw[3] = pkbf(s1[2], s1[3]);
        pw[4] = pkbf(s2[0], s2[1]); pw[5] = pkbf(s2[2], s2[3]);
        pw[6] = pkbf(s3[0], s3[1]); pw[7] = pkbf(s3[2], s3[3]);
    };

    for (int kt = 0; kt < SEQ / 64; ++kt) {
        const int kvb = kt * 64;
        __syncthreads();
        // K1,K2: 16 chunks of 1024B via global_load_lds
#pragma unroll
        for (int i = 0; i < 4; ++i) {
            const int c = wave * 4 + i;
            const int t = c >> 3, ch = c & 7;
            const char* kb = t ? k2p : k1p;
            gload16(kb + (size_t)(kvb + ch * 8 + lrow8) * 128 + scol,
                    (t ? K2s : K1s) + ch * 1024);
        }
        // V^T: reg-staged, column-permuted (kv run = 8G + 4jh + g at u = 8G+2g+jh)
        uint2 vv[4];
#pragma unroll
        for (int i = 0; i < 4; ++i) {
            const int u = (tid & 3) * 4 + i;
            const int G = u >> 3, gg = (u >> 1) & 3, jh = u & 1;
            const int kvrun = 8 * G + 4 * jh + gg;
            vv[i] = *(const uint2*)(vsrc + (size_t)(kvb + kvrun * 4) * 2);
        }
#pragma unroll
        for (int i = 0; i < 4; ++i) {
            const int u = (tid & 3) * 4 + i;
            *(uint2*)(vdst + ((u * 8) ^ vswz)) = vv[i];
        }
        __syncthreads();

        unsigned p1w[8], p2w[8];
        qk_sm(K1s, qf1, o1, m1, l1, p1w);
        qk_sm(K2s, qf2, o2, m2, l2, p2w);

        __builtin_amdgcn_s_setprio(1);
#pragma unroll
        for (int G = 0; G < 2; ++G) {
            union { unsigned u[4]; bf16x8 v; } pf1, pf2;
            pf1.u[0] = p1w[G * 4 + 0]; pf1.u[1] = p1w[G * 4 + 1];
            pf1.u[2] = p1w[G * 4 + 2]; pf1.u[3] = p1w[G * 4 + 3];
            pf2.u[0] = p2w[G * 4 + 0]; pf2.u[1] = p2w[G * 4 + 1];
            pf2.u[2] = p2w[G * 4 + 2]; pf2.u[3] = p2w[G * 4 + 3];
#pragma unroll
            for (int ds = 0; ds < 4; ++ds) {
                const int vrow = ds * 16 + fr;
                bf16x8 vf = *(const bf16x8*)(Vts + vrow * 128 +
                              ((G * 64 + g * 16) ^ ((vrow & 7) << 4)));
                o1[ds] = MFMA16(vf, pf1.v, o1[ds]);
                o2[ds] = MFMA16(vf, pf2.v, o2[ds]);
            }
        }
        __builtin_amdgcn_s_setprio(0);
    }

    const float i1 = 1.f / l1;
    const float i2 = lam / l2;
    float* op = attn_out + ((size_t)(b * SEQ + q0 + fr)) * CDIM + h * HDIM;
#pragma unroll
    for (int ds = 0; ds < 4; ++ds) {
        float4 o;
        o.x = o1[ds][0] * i1 - i2 * o2[ds][0];
        o.y = o1[ds][1] * i1 - i2 * o2[ds][1];
        o.z = o1[ds][2] * i1 - i2 * o2[ds][2];
        o.w = o1[ds][3] * i1 - i2 * o2[ds][3];
        *(float4*)(op + ds * 16 + g * 4) = o;
    }
}

// ---------------------------------------------------------------------------
// RMSNorm over last dim (1024) + 0.2 scale, fp32 in -> bf16 out.
// ---------------------------------------------------------------------------
__global__ __launch_bounds__(256) void rmsnorm_bf16(
    const float* __restrict__ in, bf16* __restrict__ out)
{
    __shared__ float red[4];
    const int row = blockIdx.x, tid = threadIdx.x;
    const float4 v = ((const float4*)(in + (size_t)row * CDIM))[tid];
    float ss = v.x * v.x + v.y * v.y + v.z * v.z + v.w * v.w;
#pragma unroll
    for (int m = 1; m < 64; m <<= 1) ss += __shfl_xor(ss, m);
    if ((tid & 63) == 0) red[tid >> 6] = ss;
    __syncthreads();
    float tot = red[0] + red[1] + red[2] + red[3];
    float sc = rsqrtf(tot * (1.f / CDIM) + EPSV) * 0.2f;
    bf16x4 o;
    o[0] = (bf16)(v.x * sc); o[1] = (bf16)(v.y * sc);
    o[2] = (bf16)(v.z * sc); o[3] = (bf16)(v.w * sc);
    ((bf16x4*)(out + (size_t)row * CDIM))[tid] = o;
}

extern "C" void kernel_launch(void* const* d_in, const int* in_sizes, int n_in,
                              void* d_out, int out_size, void* d_ws, size_t ws_size,
                              hipStream_t stream)
{
    (void)in_sizes; (void)n_in; (void)out_size; (void)ws_size;
    const float* x      = (const float*)d_in[0];
    const float* qkv_w  = (const float*)d_in[1];
    const float* proj_w = (const float*)d_in[2];
    const float* proj_b = (const float*)d_in[3];
    const float* lq1    = (const float*)d_in[4];
    const float* lk1    = (const float*)d_in[5];
    const float* lq2    = (const float*)d_in[6];
    const float* lk2    = (const float*)d_in[7];
    float* out = (float*)d_out;

    char* ws = (char*)d_ws;
    bf16*  qkv_t    = (bf16*)ws;
    bf16*  attn_b   = (bf16*)ws;
    float* attn_out = (float*)(ws + (size_t)40 * 1024 * 1024);
    bf16*  x_b      = (bf16*)(ws + (size_t)40 * 1024 * 1024);
    bf16*  qkvw_b   = (bf16*)(ws + (size_t)56 * 1024 * 1024);
    bf16*  projw_b  = (bf16*)(ws + (size_t)66 * 1024 * 1024);

    dim3 blk(256);
    cvt_bf16<<<dim3((BATCH * SEQ * CDIM) / 2048), blk, 0, stream>>>(x, x_b);
    cvt_bf16<<<dim3((QKV_F * CDIM) / 2048), blk, 0, stream>>>(qkv_w, qkvw_b);
    cvt_bf16<<<dim3((CDIM * CDIM) / 2048), blk, 0, stream>>>(proj_w, projw_b);
    gemm_lds<0><<<dim3(QKV_F / 128, (BATCH * SEQ) / 128), blk, 0, stream>>>(
        x_b, qkvw_b, nullptr, qkv_t, nullptr, BATCH * SEQ, QKV_F, CDIM);
    diff_attn<<<dim3(BATCH * NHEAD, SEQ / 64), blk, 0, stream>>>(
        qkv_t, lq1, lk1, lq2, lk2, attn_out);
    rmsnorm_bf16<<<dim3(BATCH * SEQ), blk, 0, stream>>>(attn_out, attn_b);
    gemm_lds<1><<<dim3(CDIM / 128, (BATCH * SEQ) / 128), blk, 0, stream>>>(
        attn_b, projw_b, proj_b, nullptr, out, BATCH * SEQ, CDIM, CDIM);
}